// Round 1
// baseline (650.042 us; speedup 1.0000x reference)
//
#include <hip/hip_runtime.h>
#include <hip/hip_bf16.h>
#include <math.h>

// ---------------------------------------------------------------------------
// Real spherical harmonics, l_max = 8, Wikipedia convention, (l,m) lexicographic
// index = l*l + l + m. Output (N, 81) float32, row-major.
//
// Strategy: write-BW-bound kernel (648 MB out vs ~6e8 FLOP). One thread per
// point computes all 81 values into LDS [64 pts x 81]; block then streams its
// contiguous 20736 B output region with coalesced float4 stores.
// ---------------------------------------------------------------------------

#define LMAX 8
#define NSH  81        // (LMAX+1)^2
#define BPT  64        // points per block == block size (one wave)

// ---- compile-time k(l,m) table (includes sqrt(2) for m>0) ------------------
constexpr double c_sqrt(double x) {
    double g = (x > 1.0) ? x : 1.0;
    for (int i = 0; i < 80; ++i) g = 0.5 * (g + x / g);
    return g;
}
constexpr double c_fact(int n) {
    double r = 1.0;
    for (int i = 2; i <= n; ++i) r *= (double)i;
    return r;
}
struct KTab {
    float k[LMAX + 1][LMAX + 1];   // k[l][m], m<=l
    constexpr KTab() : k{} {
        for (int l = 0; l <= LMAX; ++l)
            for (int m = 0; m <= l; ++m) {
                double v = c_sqrt((2.0 * l + 1.0) / (4.0 * 3.14159265358979323846)
                                  * c_fact(l - m) / c_fact(l + m));
                if (m > 0) v *= 1.41421356237309504880;   // sqrt(2)
                k[l][m] = (float)v;
            }
    }
};
constexpr KTab KT{};

__global__ __launch_bounds__(BPT)
void sh_kernel(const float* __restrict__ xyz, float* __restrict__ out, int n) {
    __shared__ float lds[BPT * NSH];   // 20736 B

    const int t  = threadIdx.x;
    const int p0 = blockIdx.x * BPT;
    const int p  = p0 + t;

    if (p < n) {
        const float x = xyz[3 * p + 0];
        const float y = xyz[3 * p + 1];
        const float z = xyz[3 * p + 2];

        const float r2xy = x * x + y * y;
        const float r    = sqrtf(r2xy + z * z);
        const float rxy  = sqrtf(r2xy);
        const float ct   = z / r;
        const float st   = rxy / r;
        const float irxy = (rxy > 0.0f) ? (1.0f / rxy) : 0.0f;
        const float cp   = x * irxy;
        const float sp   = y * irxy;

        // cos(m phi), sin(m phi)
        float cm[LMAX + 1], sm[LMAX + 1];
        cm[0] = 1.0f; sm[0] = 0.0f;
#pragma unroll
        for (int m = 1; m <= LMAX; ++m) {
            cm[m] = cm[m - 1] * cp - sm[m - 1] * sp;
            sm[m] = sm[m - 1] * cp + cm[m - 1] * sp;
        }

        // associated Legendre (no Condon-Shortley), P[l][m]
        float P[LMAX + 1][LMAX + 1];
        P[0][0] = 1.0f;
#pragma unroll
        for (int m = 1; m <= LMAX; ++m)
            P[m][m] = (float)(2 * m - 1) * st * P[m - 1][m - 1];
#pragma unroll
        for (int m = 0; m < LMAX; ++m)
            P[m + 1][m] = (float)(2 * m + 1) * ct * P[m][m];
#pragma unroll
        for (int m = 0; m <= LMAX; ++m) {
#pragma unroll
            for (int l = m + 2; l <= LMAX; ++l) {
                P[l][m] = ((float)(2 * l - 1) * ct * P[l - 1][m]
                           - (float)(l + m - 1) * P[l - 2][m]) * (1.0f / (float)(l - m));
            }
        }

        // emit into LDS row: bank = (17*t + j) % 32 -> 2-way across 64 lanes (free)
        float* row = &lds[t * NSH];
#pragma unroll
        for (int l = 0; l <= LMAX; ++l) {
            const int base = l * l + l;
            row[base] = KT.k[l][0] * P[l][0];
#pragma unroll
            for (int m = 1; m <= l; ++m) {
                const float kp = KT.k[l][m] * P[l][m];
                row[base + m] = kp * cm[m];
                row[base - m] = kp * sm[m];
            }
        }
    }
    __syncthreads();

    // coalesced block write: contiguous region [p0*81, (p0+valid)*81)
    const int valid = (n - p0 < BPT) ? (n - p0) : BPT;
    float* op = out + (size_t)p0 * NSH;
    if (valid == BPT) {
        // 64*81*4 = 20736 B, 16B-aligned since p0 % 64 == 0
        float4* o4 = (float4*)op;
        const float4* l4 = (const float4*)lds;
#pragma unroll 4
        for (int i = t; i < BPT * NSH / 4; i += BPT)   // 1296 float4
            o4[i] = l4[i];
    } else {
        const int nf = valid * NSH;
        for (int i = t; i < nf; i += BPT)
            op[i] = lds[i];
    }
}

extern "C" void kernel_launch(void* const* d_in, const int* in_sizes, int n_in,
                              void* d_out, int out_size, void* d_ws, size_t ws_size,
                              hipStream_t stream) {
    const float* xyz = (const float*)d_in[0];
    float*       out = (float*)d_out;
    const int n = in_sizes[0] / 3;
    const int grid = (n + BPT - 1) / BPT;
    if (grid > 0) {
        hipLaunchKernelGGL(sh_kernel, dim3(grid), dim3(BPT), 0, stream, xyz, out, n);
    }
}